// Round 2
// baseline (2155.512 us; speedup 1.0000x reference)
//
#include <hip/hip_runtime.h>
#include <cstdint>

// RingAttractorNetwork: B=2048, N_EXC=1024, N_INH=256, 10 steps.
// Inputs (f32 unless noted): 0 ext[B,1024], 1 h[B,1024], 2 sigma, 3 W_EI[1024,256],
// 4 W_IE[256,1024], 5 g_ee, 6 g_ei, 7 g_ie, 8 g_input, 9 rate_e, 10 rate_i, 11 steps(int,=10)
// Output: final r_e [B,1024] f32.
//
// RNG: replays JAX threefry with jax_threefry_partitionable=True (modern default):
//   split(key)[i]      = threefry(key, 0, i)          (fold-like split)
//   random_bits(k, 32) = h.x ^ h.y, h = threefry(k, hi(e)=0, lo(e)=e)
//   fold_in(key, t)    = threefry(key, 0, t)          (unchanged by the flag)

#define N_EXC 1024
#define N_INH 256
#define BATCH 2048
#define STEPS 10
#define MAX_POIS 32

struct U2 { uint32_t x, y; };

__device__ __forceinline__ uint32_t rotl32(uint32_t v, int r) {
  return (v << r) | (v >> (32 - r));
}

// JAX threefry2x32 (20 rounds), matches jax/_src/prng.py exactly.
__device__ __forceinline__ U2 threefry(U2 k, uint32_t x0, uint32_t x1) {
  uint32_t ks0 = k.x, ks1 = k.y, ks2 = k.x ^ k.y ^ 0x1BD11BDAu;
  x0 += ks0; x1 += ks1;
#define TF_R4(a,b,c,d) \
  x0 += x1; x1 = rotl32(x1,a); x1 ^= x0; \
  x0 += x1; x1 = rotl32(x1,b); x1 ^= x0; \
  x0 += x1; x1 = rotl32(x1,c); x1 ^= x0; \
  x0 += x1; x1 = rotl32(x1,d); x1 ^= x0;
  TF_R4(13,15,26,6)  x0 += ks1; x1 += ks2 + 1u;
  TF_R4(17,29,16,24) x0 += ks2; x1 += ks0 + 2u;
  TF_R4(13,15,26,6)  x0 += ks0; x1 += ks1 + 3u;
  TF_R4(17,29,16,24) x0 += ks1; x1 += ks2 + 4u;
  TF_R4(13,15,26,6)  x0 += ks2; x1 += ks0 + 5u;
#undef TF_R4
  U2 r; r.x = x0; r.y = x1; return r;
}

// Knuth Poisson, replaying JAX's per-iteration subkey chain (precomputed in sk[]).
// Partitionable random_bits: element e of the flat array draws
// bits = h.x ^ h.y with h = threefry(subkey, 0, e); u = bitcast((bits>>9)|0x3f800000)-1.
// Returns (poisson - lam).
__device__ __forceinline__ float poisson_mean_sub(uint32_t e,
                                                  const U2* __restrict__ sk,
                                                  float lam) {
  float neg_lam = -lam;
  float lp = 0.0f;
  int k = 0;
#pragma unroll 1
  for (int n = 0; n < MAX_POIS; ++n) {
    if (!(lp > neg_lam)) break;
    k++;
    U2 h = threefry(sk[n], 0u, e);
    uint32_t bits = h.x ^ h.y;
    float u = __uint_as_float((bits >> 9) | 0x3f800000u) - 1.0f;
    lp += logf(u);
  }
  return (float)(k - 1) - lam;
}

// Precompute subkey chains: for step t, key = fold_in(key(42), t), split -> (ke, ki),
// then iterated fold-like splits give the per-iteration uniform subkeys.
__global__ void keys_kernel(U2* subk_e, U2* subk_i) {
  int tid = threadIdx.x;
  if (tid >= 2 * STEPS) return;
  int t = tid >> 1;
  bool is_i = tid & 1;
  U2 base; base.x = 0u; base.y = 42u;                 // jax.random.key(42)
  U2 folded = threefry(base, 0u, (uint32_t)t);        // fold_in: hash (0, t)
  U2 ke = threefry(folded, 0u, 0u);                   // partitionable split: keys[0]
  U2 ki = threefry(folded, 0u, 1u);                   //                      keys[1]
  U2 rng = is_i ? ki : ke;
  U2* dst = (is_i ? subk_i : subk_e) + t * MAX_POIS;
  for (int n = 0; n < MAX_POIS; ++n) {
    dst[n] = threefry(rng, 0u, 1u);                   // subkey = keys[1]
    rng = threefry(rng, 0u, 0u);                      // rng    = keys[0]
  }
}

// W_EE ring weights: angles = linspace(0, 2pi, 1024): a_j = j * (2pi/1023);
// d = a_j - a_i wrapped via atan2(sin,cos); W = exp(-0.5 (d/sigma)^2);
// row-normalize INCLUDING diagonal, THEN zero diag.
__global__ __launch_bounds__(256) void wee_kernel(const float* __restrict__ sigma_p,
                                                  float* __restrict__ W) {
  int i = blockIdx.x;
  int tid = threadIdx.x;
  float sigma = *sigma_p;
  const float twopi = 6.28318530717958647692f;
  const float delta = twopi / 1023.0f;
  float ai = (float)i * delta;
  float w[4];
  float s = 0.0f;
#pragma unroll
  for (int q = 0; q < 4; ++q) {
    int j = tid + q * 256;
    float aj = (float)j * delta;
    float d = aj - ai;
    float wd = atan2f(sinf(d), cosf(d));
    float x = wd / sigma;
    float v = expf(-0.5f * x * x);
    w[q] = v;
    s += v;
  }
  __shared__ float red[256];
  red[tid] = s;
  __syncthreads();
  for (int off = 128; off > 0; off >>= 1) {
    if (tid < off) red[tid] += red[tid + off];
    __syncthreads();
  }
  float sum = red[0];
#pragma unroll
  for (int q = 0; q < 4; ++q) {
    int j = tid + q * 256;
    W[i * N_EXC + j] = (j == i) ? 0.0f : (w[q] / sum);
  }
}

// step_e: input_e = g_ee * (r_e @ W_EE^T) - g_ie * (r_i @ W_IE) + g_input*ext + noise_e
//         r_e' = relu(r_e + DT*(-r_e + relu(input_e))/TAU_E)
__global__ __launch_bounds__(256) void step_e_kernel(
    const float* __restrict__ re_in, const float* __restrict__ ri_in,
    const float* __restrict__ W_EE, const float* __restrict__ W_IE,
    const float* __restrict__ ext,
    const float* __restrict__ sc_gee, const float* __restrict__ sc_gie,
    const float* __restrict__ sc_gin, const float* __restrict__ sc_rate,
    const U2* __restrict__ subk, float* __restrict__ re_out) {
  __shared__ float As[64][17];
  __shared__ float Bs[64][17];
  int tid = threadIdx.x;
  int tx = tid & 15, ty = tid >> 4;
  int b0 = blockIdx.x * 64;
  int i0 = blockIdx.y * 64;

  float acc[4][4] = {};
  float acc2[4][4] = {};

  // phase 1: K = N_EXC, B[n][k] = W_EE[i0+n][k]
  for (int k0 = 0; k0 < N_EXC; k0 += 16) {
#pragma unroll
    for (int it = 0; it < 4; ++it) {
      int l = it * 256 + tid;
      int m = l >> 4, kk = l & 15;
      As[m][kk] = re_in[(b0 + m) * N_EXC + k0 + kk];
      Bs[m][kk] = W_EE[(i0 + m) * N_EXC + k0 + kk];
    }
    __syncthreads();
#pragma unroll
    for (int kk = 0; kk < 16; ++kk) {
      float a[4], b[4];
#pragma unroll
      for (int mm = 0; mm < 4; ++mm) a[mm] = As[ty + 16 * mm][kk];
#pragma unroll
      for (int nn = 0; nn < 4; ++nn) b[nn] = Bs[tx + 16 * nn][kk];
#pragma unroll
      for (int mm = 0; mm < 4; ++mm)
#pragma unroll
        for (int nn = 0; nn < 4; ++nn)
          acc[mm][nn] = fmaf(a[mm], b[nn], acc[mm][nn]);
    }
    __syncthreads();
  }

  // phase 2: K = N_INH, B[n][k] = W_IE[k][i0+n]  (skipped at t==0, r_i == 0)
  if (ri_in != nullptr) {
    for (int k0 = 0; k0 < N_INH; k0 += 16) {
#pragma unroll
      for (int it = 0; it < 4; ++it) {
        int l = it * 256 + tid;
        int m = l >> 4, kk = l & 15;
        As[m][kk] = ri_in[(b0 + m) * N_INH + k0 + kk];
        int n = l & 63, kk2 = l >> 6;
        Bs[n][kk2] = W_IE[(k0 + kk2) * N_EXC + i0 + n];
      }
      __syncthreads();
#pragma unroll
      for (int kk = 0; kk < 16; ++kk) {
        float a[4], b[4];
#pragma unroll
        for (int mm = 0; mm < 4; ++mm) a[mm] = As[ty + 16 * mm][kk];
#pragma unroll
        for (int nn = 0; nn < 4; ++nn) b[nn] = Bs[tx + 16 * nn][kk];
#pragma unroll
        for (int mm = 0; mm < 4; ++mm)
#pragma unroll
          for (int nn = 0; nn < 4; ++nn)
            acc2[mm][nn] = fmaf(a[mm], b[nn], acc2[mm][nn]);
      }
      __syncthreads();
    }
  }

  float gee = *sc_gee, gie = *sc_gie, gin = *sc_gin, rate = *sc_rate;
#pragma unroll
  for (int mm = 0; mm < 4; ++mm) {
#pragma unroll
    for (int nn = 0; nn < 4; ++nn) {
      int b = b0 + ty + 16 * mm;
      int i = i0 + tx + 16 * nn;
      int idx = b * N_EXC + i;
      float val = gee * acc[mm][nn] - gie * acc2[mm][nn] + gin * ext[idx];
      val += poisson_mean_sub((uint32_t)idx, subk, rate);
      float ro = re_in[idx];
      float rn = ro + (0.1f * (fmaxf(val, 0.0f) - ro)) / 10.0f;
      re_out[idx] = fmaxf(rn, 0.0f);
    }
  }
}

// step_i: input_i = g_ei * (r_e @ W_EI) + noise_i;
//         r_i' = relu(r_i + DT*(-r_i + relu(input_i))/TAU_I)
__global__ __launch_bounds__(256) void step_i_kernel(
    const float* __restrict__ re_in, const float* __restrict__ ri_in,
    const float* __restrict__ W_EI,
    const float* __restrict__ sc_gei, const float* __restrict__ sc_rate,
    const U2* __restrict__ subk, float* __restrict__ ri_out) {
  __shared__ float As[64][17];
  __shared__ float Bs[64][17];
  int tid = threadIdx.x;
  int tx = tid & 15, ty = tid >> 4;
  int b0 = blockIdx.x * 64;
  int i0 = blockIdx.y * 64;

  float acc[4][4] = {};
  for (int k0 = 0; k0 < N_EXC; k0 += 16) {
#pragma unroll
    for (int it = 0; it < 4; ++it) {
      int l = it * 256 + tid;
      int m = l >> 4, kk = l & 15;
      As[m][kk] = re_in[(b0 + m) * N_EXC + k0 + kk];
      int n = l & 63, kk2 = l >> 6;
      Bs[n][kk2] = W_EI[(k0 + kk2) * N_INH + i0 + n];
    }
    __syncthreads();
#pragma unroll
    for (int kk = 0; kk < 16; ++kk) {
      float a[4], b[4];
#pragma unroll
      for (int mm = 0; mm < 4; ++mm) a[mm] = As[ty + 16 * mm][kk];
#pragma unroll
      for (int nn = 0; nn < 4; ++nn) b[nn] = Bs[tx + 16 * nn][kk];
#pragma unroll
      for (int mm = 0; mm < 4; ++mm)
#pragma unroll
        for (int nn = 0; nn < 4; ++nn)
          acc[mm][nn] = fmaf(a[mm], b[nn], acc[mm][nn]);
    }
    __syncthreads();
  }

  float gei = *sc_gei, rate = *sc_rate;
#pragma unroll
  for (int mm = 0; mm < 4; ++mm) {
#pragma unroll
    for (int nn = 0; nn < 4; ++nn) {
      int b = b0 + ty + 16 * mm;
      int i = i0 + tx + 16 * nn;
      int idx = b * N_INH + i;
      float val = gei * acc[mm][nn];
      val += poisson_mean_sub((uint32_t)idx, subk, rate);
      float rio = (ri_in != nullptr) ? ri_in[idx] : 0.0f;
      float rn = rio + (0.1f * (fmaxf(val, 0.0f) - rio)) / 5.0f;
      ri_out[idx] = fmaxf(rn, 0.0f);
    }
  }
}

extern "C" void kernel_launch(void* const* d_in, const int* in_sizes, int n_in,
                              void* d_out, int out_size, void* d_ws, size_t ws_size,
                              hipStream_t stream) {
  const float* ext    = (const float*)d_in[0];
  const float* h      = (const float*)d_in[1];
  const float* sigma  = (const float*)d_in[2];
  const float* W_EI   = (const float*)d_in[3];
  const float* W_IE   = (const float*)d_in[4];
  const float* g_ee   = (const float*)d_in[5];
  const float* g_ei   = (const float*)d_in[6];
  const float* g_ie   = (const float*)d_in[7];
  const float* g_in   = (const float*)d_in[8];
  const float* rate_e = (const float*)d_in[9];
  const float* rate_i = (const float*)d_in[10];
  // d_in[11] = steps; fixed at 10 by the problem definition.

  char* ws = (char*)d_ws;
  float* W_EE = (float*)ws;  ws += (size_t)N_EXC * N_EXC * sizeof(float);   // 4 MiB
  float* reA  = (float*)ws;  ws += (size_t)BATCH * N_EXC * sizeof(float);   // 8 MiB
  float* riA  = (float*)ws;  ws += (size_t)BATCH * N_INH * sizeof(float);   // 2 MiB
  float* riB  = (float*)ws;  ws += (size_t)BATCH * N_INH * sizeof(float);   // 2 MiB
  U2* subk_e  = (U2*)ws;     ws += (size_t)STEPS * MAX_POIS * sizeof(U2);
  U2* subk_i  = (U2*)ws;     ws += (size_t)STEPS * MAX_POIS * sizeof(U2);
  float* re_dout = (float*)d_out;

  wee_kernel<<<dim3(N_EXC), dim3(256), 0, stream>>>(sigma, W_EE);
  keys_kernel<<<dim3(1), dim3(64), 0, stream>>>(subk_e, subk_i);

  for (int t = 0; t < STEPS; ++t) {
    // r_e ping-pong between reA (even-t writes) and d_out (odd-t writes):
    // t=9 (last) writes d_out.
    const float* re_in = (t == 0) ? h : ((t & 1) ? reA : re_dout);
    float* re_out      = (t & 1) ? re_dout : reA;
    const float* ri_in = (t == 0) ? nullptr : ((t & 1) ? riA : riB);
    float* ri_out      = (t & 1) ? riB : riA;

    step_i_kernel<<<dim3(BATCH / 64, N_INH / 64), dim3(256), 0, stream>>>(
        re_in, ri_in, W_EI, g_ei, rate_i, subk_i + t * MAX_POIS, ri_out);
    step_e_kernel<<<dim3(BATCH / 64, N_EXC / 64), dim3(256), 0, stream>>>(
        re_in, ri_in, W_EE, W_IE, ext, g_ee, g_ie, g_in, rate_e,
        subk_e + t * MAX_POIS, re_out);
  }
}

// Round 3
// 500.064 us; speedup vs baseline: 4.3105x; 4.3105x over previous
//
#include <hip/hip_runtime.h>
#include <cstdint>

// RingAttractorNetwork: B=2048, N_EXC=1024, N_INH=256, 10 steps.
// Round 3: bf16-MFMA GEMMs (f32 state recurrence kept exactly), fused e+i step kernel.
// RNG replays JAX threefry with jax_threefry_partitionable=True (verified round 2).

#define N_EXC 1024
#define N_INH 256
#define BATCH 2048
#define STEPS 10
#define MAX_POIS 32

typedef short s16x8 __attribute__((ext_vector_type(8)));
typedef float f32x4 __attribute__((ext_vector_type(4)));

struct U2 { uint32_t x, y; };

__device__ __forceinline__ uint32_t rotl32(uint32_t v, int r) {
  return (v << r) | (v >> (32 - r));
}

// JAX threefry2x32 (20 rounds).
__device__ __forceinline__ U2 threefry(U2 k, uint32_t x0, uint32_t x1) {
  uint32_t ks0 = k.x, ks1 = k.y, ks2 = k.x ^ k.y ^ 0x1BD11BDAu;
  x0 += ks0; x1 += ks1;
#define TF_R4(a,b,c,d) \
  x0 += x1; x1 = rotl32(x1,a); x1 ^= x0; \
  x0 += x1; x1 = rotl32(x1,b); x1 ^= x0; \
  x0 += x1; x1 = rotl32(x1,c); x1 ^= x0; \
  x0 += x1; x1 = rotl32(x1,d); x1 ^= x0;
  TF_R4(13,15,26,6)  x0 += ks1; x1 += ks2 + 1u;
  TF_R4(17,29,16,24) x0 += ks2; x1 += ks0 + 2u;
  TF_R4(13,15,26,6)  x0 += ks0; x1 += ks1 + 3u;
  TF_R4(17,29,16,24) x0 += ks1; x1 += ks2 + 4u;
  TF_R4(13,15,26,6)  x0 += ks2; x1 += ks0 + 5u;
#undef TF_R4
  U2 r; r.x = x0; r.y = x1; return r;
}

// Knuth Poisson with partitionable random_bits: bits = h.x ^ h.y, h = threefry(sk, 0, e).
__device__ __forceinline__ float poisson_mean_sub(uint32_t e,
                                                  const U2* __restrict__ sk,
                                                  float lam) {
  float neg_lam = -lam;
  float lp = 0.0f;
  int k = 0;
#pragma unroll 1
  for (int n = 0; n < MAX_POIS; ++n) {
    if (!(lp > neg_lam)) break;
    k++;
    U2 h = threefry(sk[n], 0u, e);
    uint32_t bits = h.x ^ h.y;
    float u = __uint_as_float((bits >> 9) | 0x3f800000u) - 1.0f;
    lp += logf(u);
  }
  return (float)(k - 1) - lam;
}

__device__ __forceinline__ unsigned short f2b(float f) {
  uint32_t u = __float_as_uint(f);
  return (unsigned short)((u + 0x7FFFu + ((u >> 16) & 1u)) >> 16);  // RNE
}

__global__ void keys_kernel(U2* subk_e, U2* subk_i) {
  int tid = threadIdx.x;
  if (tid >= 2 * STEPS) return;
  int t = tid >> 1;
  bool is_i = tid & 1;
  U2 base; base.x = 0u; base.y = 42u;
  U2 folded = threefry(base, 0u, (uint32_t)t);        // fold_in
  U2 ke = threefry(folded, 0u, 0u);                   // partitionable split
  U2 ki = threefry(folded, 0u, 1u);
  U2 rng = is_i ? ki : ke;
  U2* dst = (is_i ? subk_i : subk_e) + t * MAX_POIS;
  for (int n = 0; n < MAX_POIS; ++n) {
    dst[n] = threefry(rng, 0u, 1u);                   // subkey
    rng = threefry(rng, 0u, 0u);                      // carried rng
  }
}

// W_EE ring weights -> bf16. Row-normalize (incl. diagonal) in f32, then zero diag.
__global__ __launch_bounds__(256) void wee_kernel(const float* __restrict__ sigma_p,
                                                  unsigned short* __restrict__ W) {
  int i = blockIdx.x;
  int tid = threadIdx.x;
  float sigma = *sigma_p;
  const float twopi = 6.28318530717958647692f;
  const float delta = twopi / 1023.0f;
  float ai = (float)i * delta;
  float w[4];
  float s = 0.0f;
#pragma unroll
  for (int q = 0; q < 4; ++q) {
    int j = tid + q * 256;
    float aj = (float)j * delta;
    float d = aj - ai;
    float wd = atan2f(sinf(d), cosf(d));
    float x = wd / sigma;
    float v = expf(-0.5f * x * x);
    w[q] = v;
    s += v;
  }
  __shared__ float red[256];
  red[tid] = s;
  __syncthreads();
  for (int off = 128; off > 0; off >>= 1) {
    if (tid < off) red[tid] += red[tid + off];
    __syncthreads();
  }
  float sum = red[0];
#pragma unroll
  for (int q = 0; q < 4; ++q) {
    int j = tid + q * 256;
    W[i * N_EXC + j] = (j == i) ? (unsigned short)0 : f2b(w[q] / sum);
  }
}

// Transposed/converted weights + h->bf16.
__global__ void setup_kernel(const float* __restrict__ W_EI, const float* __restrict__ W_IE,
                             const float* __restrict__ h,
                             unsigned short* __restrict__ W_EIT,   // [256][1024]
                             unsigned short* __restrict__ W_IET,   // [1024][256]
                             unsigned short* __restrict__ hb) {
  int tid = blockIdx.x * blockDim.x + threadIdx.x;
  int nt = gridDim.x * blockDim.x;
  for (int i = tid; i < BATCH * N_EXC; i += nt) hb[i] = f2b(h[i]);
  for (int i = tid; i < N_INH * N_EXC; i += nt) {
    int r = i >> 10, c = i & 1023;
    W_EIT[i] = f2b(W_EI[c * N_INH + r]);
  }
  for (int i = tid; i < N_EXC * N_INH; i += nt) {
    int r = i >> 8, c = i & 255;
    W_IET[i] = f2b(W_IE[c * N_EXC + r]);
  }
}

// One K=64 tile pass: stage A[64][64],B[64][64] bf16 into padded LDS, 16x16x32 MFMAs.
// Same lane->k mapping for A and B fragments (any consistent permutation sums equal).
#define GEMM_PHASE(APTR, LDA, AROW0, BPTR, LDB, BROW0, KLEN, ACC)              \
  for (int k0 = 0; k0 < (KLEN); k0 += 64) {                                    \
    _Pragma("unroll")                                                          \
    for (int p = 0; p < 2; ++p) {                                              \
      int l = p * 256 + tid;                                                   \
      int r = l >> 3, c8 = (l & 7) << 3;                                       \
      *(s16x8*)&As[r][c8] =                                                    \
          *(const s16x8*)&(APTR)[(size_t)((AROW0) + r) * (LDA) + k0 + c8];     \
      *(s16x8*)&Bs[r][c8] =                                                    \
          *(const s16x8*)&(BPTR)[(size_t)((BROW0) + r) * (LDB) + k0 + c8];     \
    }                                                                          \
    __syncthreads();                                                           \
    _Pragma("unroll")                                                          \
    for (int ks = 0; ks < 2; ++ks) {                                           \
      s16x8 afr0 = *(const s16x8*)&As[wr * 32 + l16][ks * 32 + lhi * 8];       \
      s16x8 afr1 = *(const s16x8*)&As[wr * 32 + 16 + l16][ks * 32 + lhi * 8];  \
      s16x8 bfr0 = *(const s16x8*)&Bs[wc * 32 + l16][ks * 32 + lhi * 8];       \
      s16x8 bfr1 = *(const s16x8*)&Bs[wc * 32 + 16 + l16][ks * 32 + lhi * 8];  \
      ACC[0][0] = __builtin_amdgcn_mfma_f32_16x16x32_bf16(afr0, bfr0, ACC[0][0], 0, 0, 0); \
      ACC[0][1] = __builtin_amdgcn_mfma_f32_16x16x32_bf16(afr0, bfr1, ACC[0][1], 0, 0, 0); \
      ACC[1][0] = __builtin_amdgcn_mfma_f32_16x16x32_bf16(afr1, bfr0, ACC[1][0], 0, 0, 0); \
      ACC[1][1] = __builtin_amdgcn_mfma_f32_16x16x32_bf16(afr1, bfr1, ACC[1][1], 0, 0, 0); \
    }                                                                          \
    __syncthreads();                                                           \
  }

// Fused step: blockIdx.y<16 -> e-columns (two GEMM phases), else i-columns (one phase).
__global__ __launch_bounds__(256) void step_kernel(
    const float* __restrict__ re_in, const unsigned short* __restrict__ reb_in,
    const float* __restrict__ ri_in, const unsigned short* __restrict__ rib_in,
    const unsigned short* __restrict__ W_EEb, const unsigned short* __restrict__ W_IET,
    const unsigned short* __restrict__ W_EIT,
    const float* __restrict__ ext,
    const float* __restrict__ sc_gee, const float* __restrict__ sc_gei,
    const float* __restrict__ sc_gie, const float* __restrict__ sc_gin,
    const float* __restrict__ sc_rate_e, const float* __restrict__ sc_rate_i,
    const U2* __restrict__ subk_e, const U2* __restrict__ subk_i,
    float* __restrict__ re_out, unsigned short* __restrict__ reb_out,
    float* __restrict__ ri_out, unsigned short* __restrict__ rib_out) {
  __shared__ __align__(16) short As[64][72];   // +8 pad: 2-way banks only (free)
  __shared__ __align__(16) short Bs[64][72];
  int tid = threadIdx.x;
  int lane = tid & 63;
  int wave = tid >> 6;
  int wr = wave >> 1, wc = wave & 1;
  int l16 = lane & 15, lhi = lane >> 4;
  int b0 = blockIdx.x * 64;
  bool is_e = blockIdx.y < 16;
  int i0 = (is_e ? blockIdx.y : (blockIdx.y - 16)) * 64;

  f32x4 acc[2][2] = {};
  f32x4 acc2[2][2] = {};

  if (is_e) {
    GEMM_PHASE(reb_in, N_EXC, b0, W_EEb, N_EXC, i0, N_EXC, acc);
    if (rib_in != nullptr) {
      GEMM_PHASE(rib_in, N_INH, b0, W_IET, N_INH, i0, N_INH, acc2);
    }
    float gee = *sc_gee, gie = *sc_gie, gin = *sc_gin, rate = *sc_rate_e;
#pragma unroll
    for (int mm = 0; mm < 2; ++mm)
#pragma unroll
      for (int nn = 0; nn < 2; ++nn)
#pragma unroll
        for (int q = 0; q < 4; ++q) {
          int row = b0 + wr * 32 + mm * 16 + lhi * 4 + q;   // C/D: row=(lane>>4)*4+reg
          int col = i0 + wc * 32 + nn * 16 + l16;           //      col=lane&15
          int idx = row * N_EXC + col;
          float val = gee * acc[mm][nn][q] - gie * acc2[mm][nn][q] + gin * ext[idx];
          val += poisson_mean_sub((uint32_t)idx, subk_e, rate);
          float ro = re_in[idx];
          float rn = ro + (0.1f * (fmaxf(val, 0.0f) - ro)) / 10.0f;
          rn = fmaxf(rn, 0.0f);
          re_out[idx] = rn;
          reb_out[idx] = f2b(rn);
        }
  } else {
    GEMM_PHASE(reb_in, N_EXC, b0, W_EIT, N_EXC, i0, N_EXC, acc);
    float gei = *sc_gei, rate = *sc_rate_i;
#pragma unroll
    for (int mm = 0; mm < 2; ++mm)
#pragma unroll
      for (int nn = 0; nn < 2; ++nn)
#pragma unroll
        for (int q = 0; q < 4; ++q) {
          int row = b0 + wr * 32 + mm * 16 + lhi * 4 + q;
          int col = i0 + wc * 32 + nn * 16 + l16;
          int idx = row * N_INH + col;
          float val = gei * acc[mm][nn][q];
          val += poisson_mean_sub((uint32_t)idx, subk_i, rate);
          float rio = (ri_in != nullptr) ? ri_in[idx] : 0.0f;
          float rn = rio + (0.1f * (fmaxf(val, 0.0f) - rio)) / 5.0f;
          rn = fmaxf(rn, 0.0f);
          ri_out[idx] = rn;
          rib_out[idx] = f2b(rn);
        }
  }
}

extern "C" void kernel_launch(void* const* d_in, const int* in_sizes, int n_in,
                              void* d_out, int out_size, void* d_ws, size_t ws_size,
                              hipStream_t stream) {
  const float* ext    = (const float*)d_in[0];
  const float* h      = (const float*)d_in[1];
  const float* sigma  = (const float*)d_in[2];
  const float* W_EI   = (const float*)d_in[3];
  const float* W_IE   = (const float*)d_in[4];
  const float* g_ee   = (const float*)d_in[5];
  const float* g_ei   = (const float*)d_in[6];
  const float* g_ie   = (const float*)d_in[7];
  const float* g_in   = (const float*)d_in[8];
  const float* rate_e = (const float*)d_in[9];
  const float* rate_i = (const float*)d_in[10];

  char* ws = (char*)d_ws;
  unsigned short* W_EEb = (unsigned short*)ws; ws += (size_t)N_EXC * N_EXC * 2;   // 2 MiB
  unsigned short* W_EIT = (unsigned short*)ws; ws += (size_t)N_INH * N_EXC * 2;   // 0.5
  unsigned short* W_IET = (unsigned short*)ws; ws += (size_t)N_EXC * N_INH * 2;   // 0.5
  float* reA            = (float*)ws;          ws += (size_t)BATCH * N_EXC * 4;   // 8
  unsigned short* rebA  = (unsigned short*)ws; ws += (size_t)BATCH * N_EXC * 2;   // 4
  unsigned short* rebB  = (unsigned short*)ws; ws += (size_t)BATCH * N_EXC * 2;   // 4 (=hb)
  float* riA            = (float*)ws;          ws += (size_t)BATCH * N_INH * 4;   // 2
  float* riB            = (float*)ws;          ws += (size_t)BATCH * N_INH * 4;   // 2
  unsigned short* ribA  = (unsigned short*)ws; ws += (size_t)BATCH * N_INH * 2;   // 1
  unsigned short* ribB  = (unsigned short*)ws; ws += (size_t)BATCH * N_INH * 2;   // 1
  U2* subk_e            = (U2*)ws;             ws += (size_t)STEPS * MAX_POIS * sizeof(U2);
  U2* subk_i            = (U2*)ws;             ws += (size_t)STEPS * MAX_POIS * sizeof(U2);
  float* re_dout = (float*)d_out;

  wee_kernel<<<dim3(N_EXC), dim3(256), 0, stream>>>(sigma, W_EEb);
  setup_kernel<<<dim3(512), dim3(256), 0, stream>>>(W_EI, W_IE, h, W_EIT, W_IET, rebB);
  keys_kernel<<<dim3(1), dim3(64), 0, stream>>>(subk_e, subk_i);

  for (int t = 0; t < STEPS; ++t) {
    const float* re_in          = (t == 0) ? h : ((t & 1) ? reA : re_dout);
    float* re_out               = (t & 1) ? re_dout : reA;
    const unsigned short* rb_in = (t & 1) ? rebA : rebB;   // t=0: rebB holds bf16(h)
    unsigned short* rb_out      = (t & 1) ? rebB : rebA;
    const float* ri_in          = (t == 0) ? nullptr : ((t & 1) ? riA : riB);
    float* ri_out               = (t & 1) ? riB : riA;
    const unsigned short* ib_in = (t == 0) ? nullptr : ((t & 1) ? ribA : ribB);
    unsigned short* ib_out      = (t & 1) ? ribB : ribA;

    step_kernel<<<dim3(BATCH / 64, 20), dim3(256), 0, stream>>>(
        re_in, rb_in, ri_in, ib_in, W_EEb, W_IET, W_EIT, ext,
        g_ee, g_ei, g_ie, g_in, rate_e, rate_i,
        subk_e + t * MAX_POIS, subk_i + t * MAX_POIS,
        re_out, rb_out, ri_out, ib_out);
  }
}

// Round 4
// 394.978 us; speedup vs baseline: 5.4573x; 1.2661x over previous
//
#include <hip/hip_runtime.h>
#include <cstdint>

// RingAttractorNetwork: B=2048, N_EXC=1024, N_INH=256, 10 steps.
// Round 4: global_load_lds + double-buffered prefetch pipeline + XOR-swizzled LDS
// (T3-minimal 2-phase). Numerics identical to round 3 (passed, absmax 0.0078).

#define N_EXC 1024
#define N_INH 256
#define BATCH 2048
#define STEPS 10
#define MAX_POIS 32

typedef short s16x8 __attribute__((ext_vector_type(8)));
typedef float f32x4 __attribute__((ext_vector_type(4)));

typedef __attribute__((address_space(1))) const void GV;
typedef __attribute__((address_space(3))) void LV;

struct U2 { uint32_t x, y; };

__device__ __forceinline__ uint32_t rotl32(uint32_t v, int r) {
  return (v << r) | (v >> (32 - r));
}

// JAX threefry2x32 (20 rounds).
__device__ __forceinline__ U2 threefry(U2 k, uint32_t x0, uint32_t x1) {
  uint32_t ks0 = k.x, ks1 = k.y, ks2 = k.x ^ k.y ^ 0x1BD11BDAu;
  x0 += ks0; x1 += ks1;
#define TF_R4(a,b,c,d) \
  x0 += x1; x1 = rotl32(x1,a); x1 ^= x0; \
  x0 += x1; x1 = rotl32(x1,b); x1 ^= x0; \
  x0 += x1; x1 = rotl32(x1,c); x1 ^= x0; \
  x0 += x1; x1 = rotl32(x1,d); x1 ^= x0;
  TF_R4(13,15,26,6)  x0 += ks1; x1 += ks2 + 1u;
  TF_R4(17,29,16,24) x0 += ks2; x1 += ks0 + 2u;
  TF_R4(13,15,26,6)  x0 += ks0; x1 += ks1 + 3u;
  TF_R4(17,29,16,24) x0 += ks1; x1 += ks2 + 4u;
  TF_R4(13,15,26,6)  x0 += ks2; x1 += ks0 + 5u;
#undef TF_R4
  U2 r; r.x = x0; r.y = x1; return r;
}

// Knuth Poisson with partitionable random_bits: bits = h.x ^ h.y, h = threefry(sk, 0, e).
__device__ __forceinline__ float poisson_mean_sub(uint32_t e,
                                                  const U2* __restrict__ sk,
                                                  float lam) {
  float neg_lam = -lam;
  float lp = 0.0f;
  int k = 0;
#pragma unroll 1
  for (int n = 0; n < MAX_POIS; ++n) {
    if (!(lp > neg_lam)) break;
    k++;
    U2 h = threefry(sk[n], 0u, e);
    uint32_t bits = h.x ^ h.y;
    float u = __uint_as_float((bits >> 9) | 0x3f800000u) - 1.0f;
    lp += logf(u);
  }
  return (float)(k - 1) - lam;
}

__device__ __forceinline__ unsigned short f2b(float f) {
  uint32_t u = __float_as_uint(f);
  return (unsigned short)((u + 0x7FFFu + ((u >> 16) & 1u)) >> 16);  // RNE
}

__device__ __forceinline__ void gload16(const void* g, void* l) {
  __builtin_amdgcn_global_load_lds((GV*)g, (LV*)l, 16, 0, 0);
}

__global__ void keys_kernel(U2* subk_e, U2* subk_i) {
  int tid = threadIdx.x;
  if (tid >= 2 * STEPS) return;
  int t = tid >> 1;
  bool is_i = tid & 1;
  U2 base; base.x = 0u; base.y = 42u;
  U2 folded = threefry(base, 0u, (uint32_t)t);        // fold_in
  U2 ke = threefry(folded, 0u, 0u);                   // partitionable split
  U2 ki = threefry(folded, 0u, 1u);
  U2 rng = is_i ? ki : ke;
  U2* dst = (is_i ? subk_i : subk_e) + t * MAX_POIS;
  for (int n = 0; n < MAX_POIS; ++n) {
    dst[n] = threefry(rng, 0u, 1u);                   // subkey
    rng = threefry(rng, 0u, 0u);                      // carried rng
  }
}

// W_EE ring weights -> bf16. Row-normalize (incl. diagonal) in f32, then zero diag.
__global__ __launch_bounds__(256) void wee_kernel(const float* __restrict__ sigma_p,
                                                  unsigned short* __restrict__ W) {
  int i = blockIdx.x;
  int tid = threadIdx.x;
  float sigma = *sigma_p;
  const float twopi = 6.28318530717958647692f;
  const float delta = twopi / 1023.0f;
  float ai = (float)i * delta;
  float w[4];
  float s = 0.0f;
#pragma unroll
  for (int q = 0; q < 4; ++q) {
    int j = tid + q * 256;
    float aj = (float)j * delta;
    float d = aj - ai;
    float wd = atan2f(sinf(d), cosf(d));
    float x = wd / sigma;
    float v = expf(-0.5f * x * x);
    w[q] = v;
    s += v;
  }
  __shared__ float red[256];
  red[tid] = s;
  __syncthreads();
  for (int off = 128; off > 0; off >>= 1) {
    if (tid < off) red[tid] += red[tid + off];
    __syncthreads();
  }
  float sum = red[0];
#pragma unroll
  for (int q = 0; q < 4; ++q) {
    int j = tid + q * 256;
    W[i * N_EXC + j] = (j == i) ? (unsigned short)0 : f2b(w[q] / sum);
  }
}

// Transposed/converted weights + h->bf16.
__global__ void setup_kernel(const float* __restrict__ W_EI, const float* __restrict__ W_IE,
                             const float* __restrict__ h,
                             unsigned short* __restrict__ W_EIT,   // [256][1024]
                             unsigned short* __restrict__ W_IET,   // [1024][256]
                             unsigned short* __restrict__ hb) {
  int tid = blockIdx.x * blockDim.x + threadIdx.x;
  int nt = gridDim.x * blockDim.x;
  for (int i = tid; i < BATCH * N_EXC; i += nt) hb[i] = f2b(h[i]);
  for (int i = tid; i < N_INH * N_EXC; i += nt) {
    int r = i >> 10, c = i & 1023;
    W_EIT[i] = f2b(W_EI[c * N_INH + r]);
  }
  for (int i = tid; i < N_EXC * N_INH; i += nt) {
    int r = i >> 8, c = i & 255;
    W_IET[i] = f2b(W_IE[c * N_EXC + r]);
  }
}

// Pipelined 64x64-tile GEMM phase, double-buffered, gload_lds-staged, XOR-swizzled.
// LDS chunk j (16B) of a [64][64]-bf16 tile holds global (row=j>>3, col16=(j&7)^(row&7)).
// Read of logical (r,c16) -> byte (r<<7) | ((c16^(r&7))<<4).  Swizzle is an involution,
// applied on BOTH the global source (per-lane addr) and the ds_read -- rule 21.
#define PIPE_GEMM(APTR, LDA, AROW0, BPTR, LDB, BROW0, KLEN, ACC)                \
  {                                                                             \
    const int NT = (KLEN) / 64;                                                 \
    int c0 = wave * 128 + lane;                                                 \
    int c1 = c0 + 64;                                                           \
    int r0 = c0 >> 3, q0 = ((c0 & 7) ^ (r0 & 7)) << 3;                          \
    int r1 = c1 >> 3, q1 = ((c1 & 7) ^ (r1 & 7)) << 3;                          \
    const unsigned short* ap0 = (APTR) + (size_t)((AROW0) + r0) * (LDA) + q0;   \
    const unsigned short* ap1 = (APTR) + (size_t)((AROW0) + r1) * (LDA) + q1;   \
    const unsigned short* bp0 = (BPTR) + (size_t)((BROW0) + r0) * (LDB) + q0;   \
    const unsigned short* bp1 = (BPTR) + (size_t)((BROW0) + r1) * (LDB) + q1;   \
    char* la0 = (char*)As + wave * 2048;                                        \
    char* la1 = la0 + 1024;                                                     \
    char* lb0 = (char*)Bs + wave * 2048;                                        \
    char* lb1 = lb0 + 1024;                                                     \
    gload16(ap0, la0); gload16(ap1, la1);                                       \
    gload16(bp0, lb0); gload16(bp1, lb1);                                       \
    __syncthreads();                                                            \
    int cur = 0;                                                                \
    int raf0 = wr * 32 + l16, raf1 = raf0 + 16;                                 \
    int rbf0 = wc * 32 + l16, rbf1 = rbf0 + 16;                                 \
    int aA0 = (raf0 << 7) | ((lhi ^ (raf0 & 7)) << 4);                          \
    int aA1 = (raf1 << 7) | ((lhi ^ (raf1 & 7)) << 4);                          \
    int aB0 = (rbf0 << 7) | ((lhi ^ (rbf0 & 7)) << 4);                          \
    int aB1 = (rbf1 << 7) | ((lhi ^ (rbf1 & 7)) << 4);                          \
    for (int kt = 0; kt < NT; ++kt) {                                           \
      if (kt + 1 < NT) {                                                        \
        int k0 = (kt + 1) * 64;                                                 \
        int nb = (cur ^ 1) * 8192;                                              \
        gload16(ap0 + k0, la0 + nb); gload16(ap1 + k0, la1 + nb);               \
        gload16(bp0 + k0, lb0 + nb); gload16(bp1 + k0, lb1 + nb);               \
      }                                                                         \
      const char* ab = (const char*)As + cur * 8192;                            \
      const char* bb = (const char*)Bs + cur * 8192;                            \
      _Pragma("unroll")                                                         \
      for (int ks = 0; ks < 2; ++ks) {                                          \
        int kx = ks << 6;                                                       \
        s16x8 af0 = *(const s16x8*)(ab + (aA0 ^ kx));                           \
        s16x8 af1 = *(const s16x8*)(ab + (aA1 ^ kx));                           \
        s16x8 bf0 = *(const s16x8*)(bb + (aB0 ^ kx));                           \
        s16x8 bf1 = *(const s16x8*)(bb + (aB1 ^ kx));                           \
        ACC[0][0] = __builtin_amdgcn_mfma_f32_16x16x32_bf16(af0, bf0, ACC[0][0], 0, 0, 0); \
        ACC[0][1] = __builtin_amdgcn_mfma_f32_16x16x32_bf16(af0, bf1, ACC[0][1], 0, 0, 0); \
        ACC[1][0] = __builtin_amdgcn_mfma_f32_16x16x32_bf16(af1, bf0, ACC[1][0], 0, 0, 0); \
        ACC[1][1] = __builtin_amdgcn_mfma_f32_16x16x32_bf16(af1, bf1, ACC[1][1], 0, 0, 0); \
      }                                                                         \
      __syncthreads();                                                          \
      cur ^= 1;                                                                 \
    }                                                                           \
  }

// Fused step: blockIdx.y<16 -> e-columns (two GEMM phases), else i-columns (one phase).
__global__ __launch_bounds__(256) void step_kernel(
    const float* __restrict__ re_in, const unsigned short* __restrict__ reb_in,
    const float* __restrict__ ri_in, const unsigned short* __restrict__ rib_in,
    const unsigned short* __restrict__ W_EEb, const unsigned short* __restrict__ W_IET,
    const unsigned short* __restrict__ W_EIT,
    const float* __restrict__ ext,
    const float* __restrict__ sc_gee, const float* __restrict__ sc_gei,
    const float* __restrict__ sc_gie, const float* __restrict__ sc_gin,
    const float* __restrict__ sc_rate_e, const float* __restrict__ sc_rate_i,
    const U2* __restrict__ subk_e, const U2* __restrict__ subk_i,
    float* __restrict__ re_out, unsigned short* __restrict__ reb_out,
    float* __restrict__ ri_out, unsigned short* __restrict__ rib_out) {
  __shared__ __align__(16) short As[2 * 4096];   // 2 bufs x 64x64 bf16, swizzled
  __shared__ __align__(16) short Bs[2 * 4096];
  int tid = threadIdx.x;
  int lane = tid & 63;
  int wave = tid >> 6;
  int wr = wave >> 1, wc = wave & 1;
  int l16 = lane & 15, lhi = lane >> 4;
  int b0 = blockIdx.x * 64;
  bool is_e = blockIdx.y < 16;
  int i0 = (is_e ? blockIdx.y : (blockIdx.y - 16)) * 64;

  f32x4 acc[2][2] = {};
  f32x4 acc2[2][2] = {};

  if (is_e) {
    PIPE_GEMM(reb_in, N_EXC, b0, W_EEb, N_EXC, i0, N_EXC, acc);
    if (rib_in != nullptr) {
      PIPE_GEMM(rib_in, N_INH, b0, W_IET, N_INH, i0, N_INH, acc2);
    }
    float gee = *sc_gee, gie = *sc_gie, gin = *sc_gin, rate = *sc_rate_e;
#pragma unroll
    for (int mm = 0; mm < 2; ++mm)
#pragma unroll
      for (int nn = 0; nn < 2; ++nn)
#pragma unroll
        for (int q = 0; q < 4; ++q) {
          int row = b0 + wr * 32 + mm * 16 + lhi * 4 + q;   // C/D: row=(lane>>4)*4+reg
          int col = i0 + wc * 32 + nn * 16 + l16;           //      col=lane&15
          int idx = row * N_EXC + col;
          float val = gee * acc[mm][nn][q] - gie * acc2[mm][nn][q] + gin * ext[idx];
          val += poisson_mean_sub((uint32_t)idx, subk_e, rate);
          float ro = re_in[idx];
          float rn = ro + (0.1f * (fmaxf(val, 0.0f) - ro)) / 10.0f;
          rn = fmaxf(rn, 0.0f);
          re_out[idx] = rn;
          reb_out[idx] = f2b(rn);
        }
  } else {
    PIPE_GEMM(reb_in, N_EXC, b0, W_EIT, N_EXC, i0, N_EXC, acc);
    float gei = *sc_gei, rate = *sc_rate_i;
#pragma unroll
    for (int mm = 0; mm < 2; ++mm)
#pragma unroll
      for (int nn = 0; nn < 2; ++nn)
#pragma unroll
        for (int q = 0; q < 4; ++q) {
          int row = b0 + wr * 32 + mm * 16 + lhi * 4 + q;
          int col = i0 + wc * 32 + nn * 16 + l16;
          int idx = row * N_INH + col;
          float val = gei * acc[mm][nn][q];
          val += poisson_mean_sub((uint32_t)idx, subk_i, rate);
          float rio = (ri_in != nullptr) ? ri_in[idx] : 0.0f;
          float rn = rio + (0.1f * (fmaxf(val, 0.0f) - rio)) / 5.0f;
          rn = fmaxf(rn, 0.0f);
          ri_out[idx] = rn;
          rib_out[idx] = f2b(rn);
        }
  }
}

extern "C" void kernel_launch(void* const* d_in, const int* in_sizes, int n_in,
                              void* d_out, int out_size, void* d_ws, size_t ws_size,
                              hipStream_t stream) {
  const float* ext    = (const float*)d_in[0];
  const float* h      = (const float*)d_in[1];
  const float* sigma  = (const float*)d_in[2];
  const float* W_EI   = (const float*)d_in[3];
  const float* W_IE   = (const float*)d_in[4];
  const float* g_ee   = (const float*)d_in[5];
  const float* g_ei   = (const float*)d_in[6];
  const float* g_ie   = (const float*)d_in[7];
  const float* g_in   = (const float*)d_in[8];
  const float* rate_e = (const float*)d_in[9];
  const float* rate_i = (const float*)d_in[10];

  char* ws = (char*)d_ws;
  unsigned short* W_EEb = (unsigned short*)ws; ws += (size_t)N_EXC * N_EXC * 2;   // 2 MiB
  unsigned short* W_EIT = (unsigned short*)ws; ws += (size_t)N_INH * N_EXC * 2;   // 0.5
  unsigned short* W_IET = (unsigned short*)ws; ws += (size_t)N_EXC * N_INH * 2;   // 0.5
  float* reA            = (float*)ws;          ws += (size_t)BATCH * N_EXC * 4;   // 8
  unsigned short* rebA  = (unsigned short*)ws; ws += (size_t)BATCH * N_EXC * 2;   // 4
  unsigned short* rebB  = (unsigned short*)ws; ws += (size_t)BATCH * N_EXC * 2;   // 4 (=hb)
  float* riA            = (float*)ws;          ws += (size_t)BATCH * N_INH * 4;   // 2
  float* riB            = (float*)ws;          ws += (size_t)BATCH * N_INH * 4;   // 2
  unsigned short* ribA  = (unsigned short*)ws; ws += (size_t)BATCH * N_INH * 2;   // 1
  unsigned short* ribB  = (unsigned short*)ws; ws += (size_t)BATCH * N_INH * 2;   // 1
  U2* subk_e            = (U2*)ws;             ws += (size_t)STEPS * MAX_POIS * sizeof(U2);
  U2* subk_i            = (U2*)ws;             ws += (size_t)STEPS * MAX_POIS * sizeof(U2);
  float* re_dout = (float*)d_out;

  wee_kernel<<<dim3(N_EXC), dim3(256), 0, stream>>>(sigma, W_EEb);
  setup_kernel<<<dim3(512), dim3(256), 0, stream>>>(W_EI, W_IE, h, W_EIT, W_IET, rebB);
  keys_kernel<<<dim3(1), dim3(64), 0, stream>>>(subk_e, subk_i);

  for (int t = 0; t < STEPS; ++t) {
    const float* re_in          = (t == 0) ? h : ((t & 1) ? reA : re_dout);
    float* re_out               = (t & 1) ? re_dout : reA;
    const unsigned short* rb_in = (t & 1) ? rebA : rebB;   // t=0: rebB holds bf16(h)
    unsigned short* rb_out      = (t & 1) ? rebB : rebA;
    const float* ri_in          = (t == 0) ? nullptr : ((t & 1) ? riA : riB);
    float* ri_out               = (t & 1) ? riB : riA;
    const unsigned short* ib_in = (t == 0) ? nullptr : ((t & 1) ? ribA : ribB);
    unsigned short* ib_out      = (t & 1) ? ribB : ribA;

    step_kernel<<<dim3(BATCH / 64, 20), dim3(256), 0, stream>>>(
        re_in, rb_in, ri_in, ib_in, W_EEb, W_IET, W_EIT, ext,
        g_ee, g_ei, g_ie, g_in, rate_e, rate_i,
        subk_e + t * MAX_POIS, subk_i + t * MAX_POIS,
        re_out, rb_out, ri_out, ib_out);
  }
}

// Round 5
// 393.997 us; speedup vs baseline: 5.4709x; 1.0025x over previous
//
#include <hip/hip_runtime.h>
#include <cstdint>

// RingAttractorNetwork: B=2048, N_EXC=1024, N_INH=256, 10 steps.
// Round 5: barrier-first pipeline — [sync; prefetch next; compute cur] so the
// global_load_lds prefetch stays in flight across a full tile of compute instead
// of being drained by the barrier it was issued in front of (round-4 mistake).
// Numerics identical to rounds 3/4 (passed, absmax 0.0078).

#define N_EXC 1024
#define N_INH 256
#define BATCH 2048
#define STEPS 10
#define MAX_POIS 32

typedef short s16x8 __attribute__((ext_vector_type(8)));
typedef float f32x4 __attribute__((ext_vector_type(4)));

typedef __attribute__((address_space(1))) const void GV;
typedef __attribute__((address_space(3))) void LV;

struct U2 { uint32_t x, y; };

__device__ __forceinline__ uint32_t rotl32(uint32_t v, int r) {
  return (v << r) | (v >> (32 - r));
}

// JAX threefry2x32 (20 rounds).
__device__ __forceinline__ U2 threefry(U2 k, uint32_t x0, uint32_t x1) {
  uint32_t ks0 = k.x, ks1 = k.y, ks2 = k.x ^ k.y ^ 0x1BD11BDAu;
  x0 += ks0; x1 += ks1;
#define TF_R4(a,b,c,d) \
  x0 += x1; x1 = rotl32(x1,a); x1 ^= x0; \
  x0 += x1; x1 = rotl32(x1,b); x1 ^= x0; \
  x0 += x1; x1 = rotl32(x1,c); x1 ^= x0; \
  x0 += x1; x1 = rotl32(x1,d); x1 ^= x0;
  TF_R4(13,15,26,6)  x0 += ks1; x1 += ks2 + 1u;
  TF_R4(17,29,16,24) x0 += ks2; x1 += ks0 + 2u;
  TF_R4(13,15,26,6)  x0 += ks0; x1 += ks1 + 3u;
  TF_R4(17,29,16,24) x0 += ks1; x1 += ks2 + 4u;
  TF_R4(13,15,26,6)  x0 += ks2; x1 += ks0 + 5u;
#undef TF_R4
  U2 r; r.x = x0; r.y = x1; return r;
}

// Knuth Poisson with partitionable random_bits: bits = h.x ^ h.y, h = threefry(sk, 0, e).
__device__ __forceinline__ float poisson_mean_sub(uint32_t e,
                                                  const U2* __restrict__ sk,
                                                  float lam) {
  float neg_lam = -lam;
  float lp = 0.0f;
  int k = 0;
#pragma unroll 1
  for (int n = 0; n < MAX_POIS; ++n) {
    if (!(lp > neg_lam)) break;
    k++;
    U2 h = threefry(sk[n], 0u, e);
    uint32_t bits = h.x ^ h.y;
    float u = __uint_as_float((bits >> 9) | 0x3f800000u) - 1.0f;
    lp += logf(u);
  }
  return (float)(k - 1) - lam;
}

__device__ __forceinline__ unsigned short f2b(float f) {
  uint32_t u = __float_as_uint(f);
  return (unsigned short)((u + 0x7FFFu + ((u >> 16) & 1u)) >> 16);  // RNE
}

__device__ __forceinline__ void gload16(const void* g, void* l) {
  __builtin_amdgcn_global_load_lds((GV*)g, (LV*)l, 16, 0, 0);
}

__global__ void keys_kernel(U2* subk_e, U2* subk_i) {
  int tid = threadIdx.x;
  if (tid >= 2 * STEPS) return;
  int t = tid >> 1;
  bool is_i = tid & 1;
  U2 base; base.x = 0u; base.y = 42u;
  U2 folded = threefry(base, 0u, (uint32_t)t);        // fold_in
  U2 ke = threefry(folded, 0u, 0u);                   // partitionable split
  U2 ki = threefry(folded, 0u, 1u);
  U2 rng = is_i ? ki : ke;
  U2* dst = (is_i ? subk_i : subk_e) + t * MAX_POIS;
  for (int n = 0; n < MAX_POIS; ++n) {
    dst[n] = threefry(rng, 0u, 1u);                   // subkey
    rng = threefry(rng, 0u, 0u);                      // carried rng
  }
}

// W_EE ring weights -> bf16. Row-normalize (incl. diagonal) in f32, then zero diag.
__global__ __launch_bounds__(256) void wee_kernel(const float* __restrict__ sigma_p,
                                                  unsigned short* __restrict__ W) {
  int i = blockIdx.x;
  int tid = threadIdx.x;
  float sigma = *sigma_p;
  const float twopi = 6.28318530717958647692f;
  const float delta = twopi / 1023.0f;
  float ai = (float)i * delta;
  float w[4];
  float s = 0.0f;
#pragma unroll
  for (int q = 0; q < 4; ++q) {
    int j = tid + q * 256;
    float aj = (float)j * delta;
    float d = aj - ai;
    float wd = atan2f(sinf(d), cosf(d));
    float x = wd / sigma;
    float v = expf(-0.5f * x * x);
    w[q] = v;
    s += v;
  }
  __shared__ float red[256];
  red[tid] = s;
  __syncthreads();
  for (int off = 128; off > 0; off >>= 1) {
    if (tid < off) red[tid] += red[tid + off];
    __syncthreads();
  }
  float sum = red[0];
#pragma unroll
  for (int q = 0; q < 4; ++q) {
    int j = tid + q * 256;
    W[i * N_EXC + j] = (j == i) ? (unsigned short)0 : f2b(w[q] / sum);
  }
}

// Transposed/converted weights + h->bf16.
__global__ void setup_kernel(const float* __restrict__ W_EI, const float* __restrict__ W_IE,
                             const float* __restrict__ h,
                             unsigned short* __restrict__ W_EIT,   // [256][1024]
                             unsigned short* __restrict__ W_IET,   // [1024][256]
                             unsigned short* __restrict__ hb) {
  int tid = blockIdx.x * blockDim.x + threadIdx.x;
  int nt = gridDim.x * blockDim.x;
  for (int i = tid; i < BATCH * N_EXC; i += nt) hb[i] = f2b(h[i]);
  for (int i = tid; i < N_INH * N_EXC; i += nt) {
    int r = i >> 10, c = i & 1023;
    W_EIT[i] = f2b(W_EI[c * N_INH + r]);
  }
  for (int i = tid; i < N_EXC * N_INH; i += nt) {
    int r = i >> 8, c = i & 255;
    W_IET[i] = f2b(W_IE[c * N_EXC + r]);
  }
}

// Pipelined 64x64-tile GEMM phase, double-buffered, gload_lds-staged, XOR-swizzled.
// LDS chunk j (16B) of a [64][64]-bf16 tile holds global (row=j>>3, col16=(j&7)^(row&7)).
// Read of logical (r,c16) -> byte (r<<7) | ((c16^(r&7))<<4).  Swizzle applied on BOTH
// the global source (per-lane addr) and the ds_read (rule 21).
//
// Loop shape: [__syncthreads; prefetch T(kt+1)->buf^1; compute T(kt) from buf].
// The barrier's vmcnt(0) drains the prefetch issued one FULL tile earlier, so
// latency overlaps the previous tile's ds_read+MFMA. Race-free: the prefetch
// target buffer's readers all arrived at the preceding barrier, and every
// wave's tile-T loads are drained by its own barrier-waitcnt before any wave
// proceeds to read the shared tile. NTs must be EVEN so the next phase's
// prologue (buf0) never aliases the final tile's buffer (buf1).
#define PIPE_GEMM(APTR, LDA, AROW0, BPTR, LDB, BROW0, KLEN, ACC)                \
  {                                                                             \
    const int NT = (KLEN) / 64;                                                 \
    int c0 = wave * 128 + lane;                                                 \
    int c1 = c0 + 64;                                                           \
    int r0 = c0 >> 3, q0 = ((c0 & 7) ^ (r0 & 7)) << 3;                          \
    int r1 = c1 >> 3, q1 = ((c1 & 7) ^ (r1 & 7)) << 3;                          \
    const unsigned short* ap0 = (APTR) + (size_t)((AROW0) + r0) * (LDA) + q0;   \
    const unsigned short* ap1 = (APTR) + (size_t)((AROW0) + r1) * (LDA) + q1;   \
    const unsigned short* bp0 = (BPTR) + (size_t)((BROW0) + r0) * (LDB) + q0;   \
    const unsigned short* bp1 = (BPTR) + (size_t)((BROW0) + r1) * (LDB) + q1;   \
    char* la0 = (char*)As + wave * 2048;                                        \
    char* la1 = la0 + 1024;                                                     \
    char* lb0 = (char*)Bs + wave * 2048;                                        \
    char* lb1 = lb0 + 1024;                                                     \
    gload16(ap0, la0); gload16(ap1, la1);                                       \
    gload16(bp0, lb0); gload16(bp1, lb1);                                       \
    int cur = 0;                                                                \
    int raf0 = wr * 32 + l16, raf1 = raf0 + 16;                                 \
    int rbf0 = wc * 32 + l16, rbf1 = rbf0 + 16;                                 \
    int aA0 = (raf0 << 7) | ((lhi ^ (raf0 & 7)) << 4);                          \
    int aA1 = (raf1 << 7) | ((lhi ^ (raf1 & 7)) << 4);                          \
    int aB0 = (rbf0 << 7) | ((lhi ^ (rbf0 & 7)) << 4);                          \
    int aB1 = (rbf1 << 7) | ((lhi ^ (rbf1 & 7)) << 4);                          \
    for (int kt = 0; kt < NT; ++kt) {                                           \
      __syncthreads();                                                          \
      if (kt + 1 < NT) {                                                        \
        int k0 = (kt + 1) * 64;                                                 \
        int nb = (cur ^ 1) * 8192;                                              \
        gload16(ap0 + k0, la0 + nb); gload16(ap1 + k0, la1 + nb);               \
        gload16(bp0 + k0, lb0 + nb); gload16(bp1 + k0, lb1 + nb);               \
      }                                                                         \
      const char* ab = (const char*)As + cur * 8192;                            \
      const char* bb = (const char*)Bs + cur * 8192;                            \
      _Pragma("unroll")                                                         \
      for (int ks = 0; ks < 2; ++ks) {                                          \
        int kx = ks << 6;                                                       \
        s16x8 af0 = *(const s16x8*)(ab + (aA0 ^ kx));                           \
        s16x8 af1 = *(const s16x8*)(ab + (aA1 ^ kx));                           \
        s16x8 bf0 = *(const s16x8*)(bb + (aB0 ^ kx));                           \
        s16x8 bf1 = *(const s16x8*)(bb + (aB1 ^ kx));                           \
        ACC[0][0] = __builtin_amdgcn_mfma_f32_16x16x32_bf16(af0, bf0, ACC[0][0], 0, 0, 0); \
        ACC[0][1] = __builtin_amdgcn_mfma_f32_16x16x32_bf16(af0, bf1, ACC[0][1], 0, 0, 0); \
        ACC[1][0] = __builtin_amdgcn_mfma_f32_16x16x32_bf16(af1, bf0, ACC[1][0], 0, 0, 0); \
        ACC[1][1] = __builtin_amdgcn_mfma_f32_16x16x32_bf16(af1, bf1, ACC[1][1], 0, 0, 0); \
      }                                                                         \
      cur ^= 1;                                                                 \
    }                                                                           \
  }

// Fused step: blockIdx.y<16 -> e-columns (two GEMM phases), else i-columns (one phase).
__global__ __launch_bounds__(256) void step_kernel(
    const float* __restrict__ re_in, const unsigned short* __restrict__ reb_in,
    const float* __restrict__ ri_in, const unsigned short* __restrict__ rib_in,
    const unsigned short* __restrict__ W_EEb, const unsigned short* __restrict__ W_IET,
    const unsigned short* __restrict__ W_EIT,
    const float* __restrict__ ext,
    const float* __restrict__ sc_gee, const float* __restrict__ sc_gei,
    const float* __restrict__ sc_gie, const float* __restrict__ sc_gin,
    const float* __restrict__ sc_rate_e, const float* __restrict__ sc_rate_i,
    const U2* __restrict__ subk_e, const U2* __restrict__ subk_i,
    float* __restrict__ re_out, unsigned short* __restrict__ reb_out,
    float* __restrict__ ri_out, unsigned short* __restrict__ rib_out) {
  __shared__ __align__(16) short As[2 * 4096];   // 2 bufs x 64x64 bf16, swizzled
  __shared__ __align__(16) short Bs[2 * 4096];
  int tid = threadIdx.x;
  int lane = tid & 63;
  int wave = tid >> 6;
  int wr = wave >> 1, wc = wave & 1;
  int l16 = lane & 15, lhi = lane >> 4;
  int b0 = blockIdx.x * 64;
  bool is_e = blockIdx.y < 16;
  int i0 = (is_e ? blockIdx.y : (blockIdx.y - 16)) * 64;

  f32x4 acc[2][2] = {};
  f32x4 acc2[2][2] = {};

  if (is_e) {
    PIPE_GEMM(reb_in, N_EXC, b0, W_EEb, N_EXC, i0, N_EXC, acc);       // NT=16
    if (rib_in != nullptr) {
      PIPE_GEMM(rib_in, N_INH, b0, W_IET, N_INH, i0, N_INH, acc2);    // NT=4
    }
    float gee = *sc_gee, gie = *sc_gie, gin = *sc_gin, rate = *sc_rate_e;
#pragma unroll
    for (int mm = 0; mm < 2; ++mm)
#pragma unroll
      for (int nn = 0; nn < 2; ++nn)
#pragma unroll
        for (int q = 0; q < 4; ++q) {
          int row = b0 + wr * 32 + mm * 16 + lhi * 4 + q;   // C/D: row=(lane>>4)*4+reg
          int col = i0 + wc * 32 + nn * 16 + l16;           //      col=lane&15
          int idx = row * N_EXC + col;
          float val = gee * acc[mm][nn][q] - gie * acc2[mm][nn][q] + gin * ext[idx];
          val += poisson_mean_sub((uint32_t)idx, subk_e, rate);
          float ro = re_in[idx];
          float rn = ro + (0.1f * (fmaxf(val, 0.0f) - ro)) / 10.0f;
          rn = fmaxf(rn, 0.0f);
          re_out[idx] = rn;
          reb_out[idx] = f2b(rn);
        }
  } else {
    PIPE_GEMM(reb_in, N_EXC, b0, W_EIT, N_EXC, i0, N_EXC, acc);       // NT=16
    float gei = *sc_gei, rate = *sc_rate_i;
#pragma unroll
    for (int mm = 0; mm < 2; ++mm)
#pragma unroll
      for (int nn = 0; nn < 2; ++nn)
#pragma unroll
        for (int q = 0; q < 4; ++q) {
          int row = b0 + wr * 32 + mm * 16 + lhi * 4 + q;
          int col = i0 + wc * 32 + nn * 16 + l16;
          int idx = row * N_INH + col;
          float val = gei * acc[mm][nn][q];
          val += poisson_mean_sub((uint32_t)idx, subk_i, rate);
          float rio = (ri_in != nullptr) ? ri_in[idx] : 0.0f;
          float rn = rio + (0.1f * (fmaxf(val, 0.0f) - rio)) / 5.0f;
          rn = fmaxf(rn, 0.0f);
          ri_out[idx] = rn;
          rib_out[idx] = f2b(rn);
        }
  }
}

extern "C" void kernel_launch(void* const* d_in, const int* in_sizes, int n_in,
                              void* d_out, int out_size, void* d_ws, size_t ws_size,
                              hipStream_t stream) {
  const float* ext    = (const float*)d_in[0];
  const float* h      = (const float*)d_in[1];
  const float* sigma  = (const float*)d_in[2];
  const float* W_EI   = (const float*)d_in[3];
  const float* W_IE   = (const float*)d_in[4];
  const float* g_ee   = (const float*)d_in[5];
  const float* g_ei   = (const float*)d_in[6];
  const float* g_ie   = (const float*)d_in[7];
  const float* g_in   = (const float*)d_in[8];
  const float* rate_e = (const float*)d_in[9];
  const float* rate_i = (const float*)d_in[10];

  char* ws = (char*)d_ws;
  unsigned short* W_EEb = (unsigned short*)ws; ws += (size_t)N_EXC * N_EXC * 2;   // 2 MiB
  unsigned short* W_EIT = (unsigned short*)ws; ws += (size_t)N_INH * N_EXC * 2;   // 0.5
  unsigned short* W_IET = (unsigned short*)ws; ws += (size_t)N_EXC * N_INH * 2;   // 0.5
  float* reA            = (float*)ws;          ws += (size_t)BATCH * N_EXC * 4;   // 8
  unsigned short* rebA  = (unsigned short*)ws; ws += (size_t)BATCH * N_EXC * 2;   // 4
  unsigned short* rebB  = (unsigned short*)ws; ws += (size_t)BATCH * N_EXC * 2;   // 4 (=hb)
  float* riA            = (float*)ws;          ws += (size_t)BATCH * N_INH * 4;   // 2
  float* riB            = (float*)ws;          ws += (size_t)BATCH * N_INH * 4;   // 2
  unsigned short* ribA  = (unsigned short*)ws; ws += (size_t)BATCH * N_INH * 2;   // 1
  unsigned short* ribB  = (unsigned short*)ws; ws += (size_t)BATCH * N_INH * 2;   // 1
  U2* subk_e            = (U2*)ws;             ws += (size_t)STEPS * MAX_POIS * sizeof(U2);
  U2* subk_i            = (U2*)ws;             ws += (size_t)STEPS * MAX_POIS * sizeof(U2);
  float* re_dout = (float*)d_out;

  wee_kernel<<<dim3(N_EXC), dim3(256), 0, stream>>>(sigma, W_EEb);
  setup_kernel<<<dim3(512), dim3(256), 0, stream>>>(W_EI, W_IE, h, W_EIT, W_IET, rebB);
  keys_kernel<<<dim3(1), dim3(64), 0, stream>>>(subk_e, subk_i);

  for (int t = 0; t < STEPS; ++t) {
    const float* re_in          = (t == 0) ? h : ((t & 1) ? reA : re_dout);
    float* re_out               = (t & 1) ? re_dout : reA;
    const unsigned short* rb_in = (t & 1) ? rebA : rebB;   // t=0: rebB holds bf16(h)
    unsigned short* rb_out      = (t & 1) ? rebB : rebA;
    const float* ri_in          = (t == 0) ? nullptr : ((t & 1) ? riA : riB);
    float* ri_out               = (t & 1) ? riB : riA;
    const unsigned short* ib_in = (t == 0) ? nullptr : ((t & 1) ? ribA : ribB);
    unsigned short* ib_out      = (t & 1) ? ribB : ribA;

    step_kernel<<<dim3(BATCH / 64, 20), dim3(256), 0, stream>>>(
        re_in, rb_in, ri_in, ib_in, W_EEb, W_IET, W_EIT, ext,
        g_ee, g_ei, g_ie, g_in, rate_e, rate_i,
        subk_e + t * MAX_POIS, subk_i + t * MAX_POIS,
        re_out, rb_out, ri_out, ib_out);
  }
}